// Round 1
// baseline (466.812 us; speedup 1.0000x reference)
//
#include <hip/hip_runtime.h>
#include <cfloat>

#define B_   16
#define C_   256
#define K_   1024
#define HW_  4096
#define N_   (B_ * HW_)          // 65536 rows
#define CHW_ (C_ * HW_)          // 1048576

// d_out layout (floats): zq [0, 16777216), seq [16777216, 16842752), losses [16842752, 16842754)
#define SEQ_OFF  (B_ * C_ * HW_)     // 16777216
#define LOSS_OFF (SEQ_OFF + N_)      // 16842752
// staging inside the zq region (overwritten later by gather kernel):
//   w_t:  C_*K_ floats (1 MB) at out+0
//   wnorm: K_ floats at out + C_*K_

// ---------------- kernel 1: transpose weight [K][C] -> w_t [C][K] ----------------
__global__ __launch_bounds__(256) void transpose_w_kernel(
    const float* __restrict__ w, float* __restrict__ w_t)
{
    const int tid = blockIdx.x * 256 + threadIdx.x;   // 0 .. 65535 (K_*C_/4)
    const float4 v = reinterpret_cast<const float4*>(w)[tid];
    const int k = tid >> 6;            // (tid*4) / 256
    const int c = (tid & 63) * 4;
    w_t[(size_t)(c + 0) * K_ + k] = v.x;
    w_t[(size_t)(c + 1) * K_ + k] = v.y;
    w_t[(size_t)(c + 2) * K_ + k] = v.z;
    w_t[(size_t)(c + 3) * K_ + k] = v.w;
}

// ---------------- kernel 2: wnorm[k] = ||w_k||^2 ----------------
__global__ __launch_bounds__(256) void wnorm_kernel(
    const float* __restrict__ w, float* __restrict__ wn)
{
    const int k = blockIdx.x * 256 + threadIdx.x;     // 0..1023
    const float4* wr = reinterpret_cast<const float4*>(w + (size_t)k * C_);
    float s = 0.f;
#pragma unroll 8
    for (int c4 = 0; c4 < C_ / 4; ++c4) {
        const float4 v = wr[c4];
        s += v.x * v.x + v.y * v.y + v.z * v.z + v.w * v.w;
    }
    wn[k] = s;
}

// ---------------- kernel 3: argmin over codes ----------------
// Block: 256 threads (4 waves) handles 64 consecutive rows (one b, hw0..hw0+63).
// x tile staged in LDS as [c][row] (64 KB). Wave wv sweeps K-tiles kt = p*4+wv.
// Lane l: i = l&3 -> rows i*16..i*16+15 ; jj = (l>>2)&15 -> codes k0+4jj..+3.
__global__ __launch_bounds__(256) void argmin_kernel(
    const float* __restrict__ x, const float* __restrict__ w_t,
    const float* __restrict__ wnorm, float* __restrict__ seq)
{
    __shared__ float xs[C_ * 64];                     // 65536 bytes
    const int t   = threadIdx.x;
    const int nb  = blockIdx.x;                       // 0..1023
    const int b   = nb >> 6;
    const int hw0 = (nb & 63) << 6;
    const float* xb = x + (size_t)b * CHW_ + hw0;

    // stage x: 64 rows x 256 channels, coalesced float4 over rows
    {
        const int r4 = (t & 15) * 4;
        const int cg = t >> 4;                        // 0..15
#pragma unroll
        for (int cc = 0; cc < 16; ++cc) {
            const int c = cc * 16 + cg;
            const float4 v = *reinterpret_cast<const float4*>(xb + (size_t)c * HW_ + r4);
            *reinterpret_cast<float4*>(&xs[c * 64 + r4]) = v;
        }
    }
    __syncthreads();

    const int i  = t & 3;          // row group: rows i*16 .. i*16+15
    const int jj = (t >> 2) & 15;  // code group within wave
    const int wv = t >> 6;         // wave id 0..3

    float bestv[16];
    int   besti[16];
#pragma unroll
    for (int rr = 0; rr < 16; ++rr) { bestv[rr] = FLT_MAX; besti[rr] = 0; }

    const float* xp = xs + i * 16;

    for (int p = 0; p < 4; ++p) {
        const int kt = p * 4 + wv;            // this wave's K-tile (64 codes)
        const int k0 = kt * 64 + jj * 4;      // this thread's 4 codes
        const float* wp = w_t + k0;

        float acc[16][4];
#pragma unroll
        for (int rr = 0; rr < 16; ++rr)
#pragma unroll
            for (int kk = 0; kk < 4; ++kk) acc[rr][kk] = 0.f;

#pragma unroll 2
        for (int c = 0; c < C_; ++c) {
            const float4 wv4 = *reinterpret_cast<const float4*>(wp + (size_t)c * K_);
            const float wr[4] = { wv4.x, wv4.y, wv4.z, wv4.w };
            float xr[16];
#pragma unroll
            for (int iv = 0; iv < 4; ++iv) {
                const float4 xv = *reinterpret_cast<const float4*>(xp + c * 64 + iv * 4);
                xr[iv * 4 + 0] = xv.x; xr[iv * 4 + 1] = xv.y;
                xr[iv * 4 + 2] = xv.z; xr[iv * 4 + 3] = xv.w;
            }
#pragma unroll
            for (int rr = 0; rr < 16; ++rr)
#pragma unroll
                for (int kk = 0; kk < 4; ++kk)
                    acc[rr][kk] = fmaf(xr[rr], wr[kk], acc[rr][kk]);
        }

        const float4 wn4 = *reinterpret_cast<const float4*>(wnorm + k0);
        const float wnr[4] = { wn4.x, wn4.y, wn4.z, wn4.w };
#pragma unroll
        for (int rr = 0; rr < 16; ++rr) {
#pragma unroll
            for (int kk = 0; kk < 4; ++kk) {
                const float s = wnr[kk] - 2.f * acc[rr][kk];
                const int kidx = k0 + kk;
                if (s < bestv[rr] || (s == bestv[rr] && kidx < besti[rr])) {
                    bestv[rr] = s; besti[rr] = kidx;
                }
            }
        }
    }

    // reduce over jj (lane bits 2..5) within each wave
#pragma unroll
    for (int m = 0; m < 4; ++m) {
        const int mask = 4 << m;
#pragma unroll
        for (int rr = 0; rr < 16; ++rr) {
            const float ov = __shfl_xor(bestv[rr], mask, 64);
            const int   oi = __shfl_xor(besti[rr], mask, 64);
            if (ov < bestv[rr] || (ov == bestv[rr] && oi < besti[rr])) {
                bestv[rr] = ov; besti[rr] = oi;
            }
        }
    }

    // cross-wave reduce via LDS (xs reuse is safe: all waves past their reads)
    __syncthreads();
    float* bvs = xs;                                   // [4][64]
    int*   bis = reinterpret_cast<int*>(xs + 256);     // [4][64]
    if (jj == 0) {
#pragma unroll
        for (int rr = 0; rr < 16; ++rr) {
            bvs[wv * 64 + i * 16 + rr] = bestv[rr];
            bis[wv * 64 + i * 16 + rr] = besti[rr];
        }
    }
    __syncthreads();
    if (t < 64) {
        float bv = bvs[t];
        int   bi = bis[t];
#pragma unroll
        for (int w2 = 1; w2 < 4; ++w2) {
            const float v2 = bvs[w2 * 64 + t];
            const int   i2 = bis[w2 * 64 + t];
            if (v2 < bv || (v2 == bv && i2 < bi)) { bv = v2; bi = i2; }
        }
        seq[b * HW_ + hw0 + t] = (float)bi;
    }
}

// ---------------- kernel 4: gather z, write zq, accumulate loss ----------------
__global__ __launch_bounds__(256) void gather_kernel(
    const float* __restrict__ x, const float* __restrict__ w,
    const float* __restrict__ seqf, float* __restrict__ zq,
    double* __restrict__ loss_acc)
{
    const int t   = threadIdx.x;
    const int nb  = blockIdx.x;
    const int b   = nb >> 6;
    const int hw0 = (nb & 63) << 6;
    const int r   = t & 63;
    const int cg  = t >> 6;
    const float* xb = x  + (size_t)b * CHW_ + hw0;
    float*       zb = zq + (size_t)b * CHW_ + hw0;
    const int idx = (int)seqf[b * HW_ + hw0 + r];
    const float* wrow = w + (size_t)idx * C_;

    float lsum = 0.f;
#pragma unroll 4
    for (int cc = 0; cc < 64; ++cc) {
        const int c = cg * 64 + cc;
        const float xv = xb[(size_t)c * HW_ + r];
        const float d  = wrow[c] - xv;
        zb[(size_t)c * HW_ + r] = xv + d;   // zq = x + (z - x), matches ref fp ops
        lsum += d * d;
    }
#pragma unroll
    for (int off = 32; off >= 1; off >>= 1) lsum += __shfl_down(lsum, off, 64);
    __shared__ float wsum[4];
    if ((t & 63) == 0) wsum[t >> 6] = lsum;
    __syncthreads();
    if (t == 0)
        atomicAdd(loss_acc, (double)(wsum[0] + wsum[1] + wsum[2] + wsum[3]));
}

// ---------------- kernel 5: finalize losses ----------------
__global__ void finalize_kernel(const double* __restrict__ acc, float* __restrict__ loss_out)
{
    const double s = *acc;
    const float m = (float)(s / (double)((size_t)N_ * C_));
    loss_out[0] = m;   // codebook loss
    loss_out[1] = m;   // commitment loss (same forward value)
}

extern "C" void kernel_launch(void* const* d_in, const int* in_sizes, int n_in,
                              void* d_out, int out_size, void* d_ws, size_t ws_size,
                              hipStream_t stream)
{
    (void)in_sizes; (void)n_in; (void)out_size; (void)d_ws; (void)ws_size;
    const float* x = (const float*)d_in[0];
    const float* w = (const float*)d_in[1];
    float* out  = (float*)d_out;
    float* w_t  = out;                 // staged in zq region, overwritten later
    float* wn   = out + (size_t)C_ * K_;
    float* seq  = out + SEQ_OFF;
    double* loss_acc = (double*)(out + LOSS_OFF);

    transpose_w_kernel<<<256, 256, 0, stream>>>(w, w_t);
    wnorm_kernel<<<4, 256, 0, stream>>>(w, wn);
    argmin_kernel<<<1024, 256, 0, stream>>>(x, w_t, wn, seq);
    hipMemsetAsync((char*)d_out + (size_t)LOSS_OFF * 4, 0, 8, stream);
    gather_kernel<<<1024, 256, 0, stream>>>(x, w, seq, out, loss_acc);
    finalize_kernel<<<1, 1, 0, stream>>>(loss_acc, out + LOSS_OFF);
}

// Round 2
// 194.401 us; speedup vs baseline: 2.4013x; 2.4013x over previous
//
#include <hip/hip_runtime.h>
#include <cfloat>

#define B_   16
#define C_   256
#define K_   1024
#define HW_  4096
#define N_   (B_ * HW_)          // 65536 rows
#define CHW_ (C_ * HW_)          // 1048576

// d_out layout (floats): zq [0, 16777216), seq [16777216, 16842752), losses [16842752, 16842754)
#define SEQ_OFF  (B_ * C_ * HW_)     // 16777216
#define LOSS_OFF (SEQ_OFF + N_)      // 16842752
// staging inside the zq region (all overwritten by gather at the end):
//   w_t   f32 [C][K]      @ float 0        (262144)
//   wnorm f32 [K]         @ float 262144   (1024)
//   whb   bf16 [K][C]     @ float 263168   (131072 floats worth)
//   wlb   bf16 [K][C]     @ float 394240   (131072)
//   rlist int [N]         @ float 525312   (65536)
//   rcount int            @ float 590848

#define WT_F    0
#define WN_F    262144
#define WHB_F   263168
#define WLB_F   394240
#define RLIST_F 525312
#define RCNT_F  590848

#define EPS_GAP 0.03125f

typedef short bf16x8 __attribute__((ext_vector_type(8)));
typedef float f32x4  __attribute__((ext_vector_type(4)));

__device__ __forceinline__ unsigned short bf16_rne(float f) {
    unsigned u = __float_as_uint(f);
    unsigned r = u + 0x7fffu + ((u >> 16) & 1u);
    return (unsigned short)(r >> 16);
}
__device__ __forceinline__ float bf16_to_f(unsigned short h) {
    return __uint_as_float(((unsigned)h) << 16);
}
__device__ __forceinline__ int swz16k(int o) {      // XOR-swizzle within a 16KB [32][512B] tile
    return o ^ (((o >> 9) & 7) << 4);
}

// ---------------- prep 1: transpose weight [K][C] -> w_t [C][K] (f32, for rescue) ----------------
__global__ __launch_bounds__(256) void transpose_w_kernel(
    const float* __restrict__ w, float* __restrict__ w_t)
{
    const int tid = blockIdx.x * 256 + threadIdx.x;   // 0 .. 65535
    const float4 v = reinterpret_cast<const float4*>(w)[tid];
    const int k = tid >> 6;
    const int c = (tid & 63) * 4;
    w_t[(size_t)(c + 0) * K_ + k] = v.x;
    w_t[(size_t)(c + 1) * K_ + k] = v.y;
    w_t[(size_t)(c + 2) * K_ + k] = v.z;
    w_t[(size_t)(c + 3) * K_ + k] = v.w;
}

// ---------------- prep 2: wnorm[k] = ||w_k||^2 (f32 exact) ----------------
__global__ __launch_bounds__(256) void wnorm_kernel(
    const float* __restrict__ w, float* __restrict__ wn)
{
    const int k = blockIdx.x * 256 + threadIdx.x;
    const float4* wr = reinterpret_cast<const float4*>(w + (size_t)k * C_);
    float s = 0.f;
#pragma unroll 8
    for (int c4 = 0; c4 < C_ / 4; ++c4) {
        const float4 v = wr[c4];
        s += v.x * v.x + v.y * v.y + v.z * v.z + v.w * v.w;
    }
    wn[k] = s;
}

// ---------------- prep 3: split w into bf16 hi/lo, same [K][C] layout ----------------
__global__ __launch_bounds__(256) void wsplit_kernel(
    const float* __restrict__ w, unsigned short* __restrict__ whb,
    unsigned short* __restrict__ wlb)
{
    const int tid = blockIdx.x * 256 + threadIdx.x;   // 0..65535, 4 elems each
#pragma unroll
    for (int q = 0; q < 4; ++q) {
        const int i = tid * 4 + q;
        const float v = w[i];
        const unsigned short hi = bf16_rne(v);
        whb[i] = hi;
        wlb[i] = bf16_rne(v - bf16_to_f(hi));
    }
}

// ---------------- pass A: MFMA approximate argmin with gap flagging ----------------
// 256 blocks x 512 threads (8 waves). Block: 256 rows (one b, hw0..hw0+255).
// Wave wv owns rows wv*32..wv*32+31 (2 m-tiles of 16). x hi/lo A-fragments live in
// registers (128 VGPR). w hi/lo staged per 32-code chunk in LDS (double-buffered),
// XOR-swizzled via pre-swizzled global source (global_load_lds writes linearly).
__global__ __launch_bounds__(512, 2) void argmin_mfma_kernel(
    const float* __restrict__ x, const unsigned short* __restrict__ whb,
    const unsigned short* __restrict__ wlb, const float* __restrict__ wnorm,
    float* __restrict__ seq, int* __restrict__ rlist, int* __restrict__ rcount)
{
    __shared__ __align__(16) char lds[65536];   // 2 x 32KB B-chunk buffers; x-staging aliases
    const int t  = threadIdx.x;
    const int l  = t & 63;
    const int wv = t >> 6;
    const int nb = blockIdx.x;
    const int b  = nb >> 4;
    const int hw0 = (nb & 15) << 8;
    const float* xb = x + (size_t)b * CHW_ + hw0;

    const int lr = l & 15;    // A row / B col / D col lane index
    const int g  = l >> 4;    // k-group

    // ---- x setup: stage f32 tile per 32-c chunk, extract A-fragments, split to bf16 hi/lo ----
    bf16x8 ah[2][8], al[2][8];
    {
        float* xs = (float*)lds;                      // [32][272] f32 (34816 B)
#pragma unroll
        for (int cc = 0; cc < 8; ++cc) {
#pragma unroll
            for (int q = 0; q < 4; ++q) {
                const int fi = t + q * 512;           // float4 index, 2048 total
                const int cl = fi >> 6;
                const int r4 = (fi & 63) << 2;
                const float4 v = *reinterpret_cast<const float4*>(
                    xb + (size_t)(cc * 32 + cl) * HW_ + r4);
                *reinterpret_cast<float4*>(xs + cl * 272 + r4) = v;
            }
            __syncthreads();
#pragma unroll
            for (int mt = 0; mt < 2; ++mt) {
                const int row = wv * 32 + mt * 16 + lr;
                bf16x8 vh, vl;
#pragma unroll
                for (int j = 0; j < 8; ++j) {
                    const float v = xs[(g * 8 + j) * 272 + row];
                    const unsigned short hi = bf16_rne(v);
                    vh[j] = (short)hi;
                    vl[j] = (short)bf16_rne(v - bf16_to_f(hi));
                }
                ah[mt][cc] = vh;
                al[mt][cc] = vl;
            }
            __syncthreads();
        }
    }

    // ---- main loop over 32 chunks of 32 codes ----
    char* const buf0 = lds;
    char* const buf1 = lds + 32768;
    const char* whbB = (const char*)whb;
    const char* wlbB = (const char*)wlb;

    // stage chunk `ch` into buffer `dst`: [whs 16K | wls 16K], pre-swizzled source
#define STAGE_CHUNK(ch, dst)                                                        \
    {                                                                               \
        const size_t goff = (size_t)(ch) * 16384;                                   \
        _Pragma("unroll")                                                           \
        for (int rr = 0; rr < 4; ++rr) {                                            \
            const int sIdx = wv * 4 + rr;                                           \
            const int region = sIdx >> 4;                                           \
            const int L = (sIdx & 15) * 1024;                                       \
            const int sw = swz16k(L + l * 16);                                      \
            const char* gp = (region ? wlbB : whbB) + goff + sw;                    \
            char* lp = (dst) + region * 16384 + L;                                  \
            __builtin_amdgcn_global_load_lds(                                       \
                (const __attribute__((address_space(1))) void*)gp,                  \
                (__attribute__((address_space(3))) void*)lp, 16, 0, 0);             \
        }                                                                           \
    }

    STAGE_CHUNK(0, buf0);
    __syncthreads();

    float m1v[2][4], m2v[2][4];
    int   i1v[2][4];
#pragma unroll
    for (int mt = 0; mt < 2; ++mt)
#pragma unroll
        for (int i = 0; i < 4; ++i) { m1v[mt][i] = FLT_MAX; m2v[mt][i] = FLT_MAX; i1v[mt][i] = 0; }

    int cur = 0;
    for (int ch = 0; ch < 32; ++ch) {
        char* const curbuf = cur ? buf1 : buf0;
        if (ch < 31) { STAGE_CHUNK(ch + 1, cur ? buf0 : buf1); }
        const int k0 = ch * 32;
        const float wn0 = wnorm[k0 + lr];
        const float wn1 = wnorm[k0 + 16 + lr];

        f32x4 acc[2][2];
#pragma unroll
        for (int mt = 0; mt < 2; ++mt)
#pragma unroll
            for (int nt = 0; nt < 2; ++nt) acc[mt][nt] = (f32x4){0.f, 0.f, 0.f, 0.f};

        const char* whs = curbuf;
        const char* wls = curbuf + 16384;
#pragma unroll
        for (int nt = 0; nt < 2; ++nt) {
#pragma unroll
            for (int s = 0; s < 8; ++s) {
                const int E = (nt * 16 + lr) * 512 + s * 64 + g * 16;
                const int sw = swz16k(E);
                const bf16x8 bh = *reinterpret_cast<const bf16x8*>(whs + sw);
                const bf16x8 bl = *reinterpret_cast<const bf16x8*>(wls + sw);
                acc[0][nt] = __builtin_amdgcn_mfma_f32_16x16x32_bf16(ah[0][s], bh, acc[0][nt], 0, 0, 0);
                acc[1][nt] = __builtin_amdgcn_mfma_f32_16x16x32_bf16(ah[1][s], bh, acc[1][nt], 0, 0, 0);
                acc[0][nt] = __builtin_amdgcn_mfma_f32_16x16x32_bf16(al[0][s], bh, acc[0][nt], 0, 0, 0);
                acc[1][nt] = __builtin_amdgcn_mfma_f32_16x16x32_bf16(al[1][s], bh, acc[1][nt], 0, 0, 0);
                acc[0][nt] = __builtin_amdgcn_mfma_f32_16x16x32_bf16(ah[0][s], bl, acc[0][nt], 0, 0, 0);
                acc[1][nt] = __builtin_amdgcn_mfma_f32_16x16x32_bf16(ah[1][s], bl, acc[1][nt], 0, 0, 0);
            }
        }

        // epilogue: d = wn - 2*dot, update per-row (min1, idx1, min2)
#pragma unroll
        for (int mt = 0; mt < 2; ++mt) {
#pragma unroll
            for (int nt = 0; nt < 2; ++nt) {
                const float wn = nt ? wn1 : wn0;
                const int k = k0 + nt * 16 + lr;
#pragma unroll
                for (int i = 0; i < 4; ++i) {
                    const float d = fmaf(-2.f, acc[mt][nt][i], wn);
                    const bool lt = d < m1v[mt][i];
                    const float nm2 = lt ? m1v[mt][i] : fminf(m2v[mt][i], d);
                    i1v[mt][i] = lt ? k : i1v[mt][i];
                    m1v[mt][i] = lt ? d : m1v[mt][i];
                    m2v[mt][i] = nm2;
                }
            }
        }
        __syncthreads();
        cur ^= 1;
    }
#undef STAGE_CHUNK

    // cross-lane merge over the 16 code lanes (lane bits 0..3)
#pragma unroll
    for (int mask = 1; mask <= 8; mask <<= 1) {
#pragma unroll
        for (int mt = 0; mt < 2; ++mt) {
#pragma unroll
            for (int i = 0; i < 4; ++i) {
                const float om1 = __shfl_xor(m1v[mt][i], mask, 64);
                const int   oi1 = __shfl_xor(i1v[mt][i], mask, 64);
                const float om2 = __shfl_xor(m2v[mt][i], mask, 64);
                const bool lt = om1 < m1v[mt][i];
                const float nm2 = lt ? fminf(m1v[mt][i], om2) : fminf(m2v[mt][i], om1);
                i1v[mt][i] = lt ? oi1 : i1v[mt][i];
                m1v[mt][i] = lt ? om1 : m1v[mt][i];
                m2v[mt][i] = nm2;
            }
        }
    }

    if (lr == 0) {
#pragma unroll
        for (int mt = 0; mt < 2; ++mt) {
#pragma unroll
            for (int i = 0; i < 4; ++i) {
                const int m = mt * 16 + g * 4 + i;          // row within wave tile (0..31)
                const int n = b * HW_ + hw0 + wv * 32 + m;  // global row id
                seq[n] = (float)i1v[mt][i];
                if (m2v[mt][i] - m1v[mt][i] < EPS_GAP) {
                    const int pos = atomicAdd(rcount, 1);
                    rlist[pos] = n;
                }
            }
        }
    }
}

// ---------------- rescue: exact f32 re-argmin for flagged rows ----------------
__global__ __launch_bounds__(256) void rescue_kernel(
    const float* __restrict__ x, const float* __restrict__ w_t,
    const float* __restrict__ wnorm, const int* __restrict__ rlist,
    const int* __restrict__ rcount, float* __restrict__ seq)
{
    __shared__ float xr[C_];
    __shared__ float bvs[4];
    __shared__ int   bis[4];
    const int t = threadIdx.x;
    const int cnt = *rcount;
    for (int ii = blockIdx.x; ii < cnt; ii += gridDim.x) {
        const int n = rlist[ii];
        const int b = n >> 12, hw = n & 4095;
        xr[t] = x[(size_t)b * CHW_ + (size_t)t * HW_ + hw];
        __syncthreads();
        float best = FLT_MAX; int bidx = 0;
#pragma unroll
        for (int q = 0; q < 4; ++q) {
            const int k = t + q * 256;
            float acc = 0.f;
            for (int c = 0; c < C_; ++c) acc = fmaf(xr[c], w_t[(size_t)c * K_ + k], acc);
            const float d = wnorm[k] - 2.f * acc;
            if (d < best || (d == best && k < bidx)) { best = d; bidx = k; }
        }
#pragma unroll
        for (int mask = 1; mask < 64; mask <<= 1) {
            const float ov = __shfl_xor(best, mask, 64);
            const int   oi = __shfl_xor(bidx, mask, 64);
            if (ov < best || (ov == best && oi < bidx)) { best = ov; bidx = oi; }
        }
        if ((t & 63) == 0) { bvs[t >> 6] = best; bis[t >> 6] = bidx; }
        __syncthreads();
        if (t == 0) {
            float bv = bvs[0]; int bi = bis[0];
#pragma unroll
            for (int w2 = 1; w2 < 4; ++w2)
                if (bvs[w2] < bv || (bvs[w2] == bv && bis[w2] < bi)) { bv = bvs[w2]; bi = bis[w2]; }
            seq[n] = (float)bi;
        }
        __syncthreads();
    }
}

// ---------------- gather z, write zq, accumulate loss ----------------
__global__ __launch_bounds__(256) void gather_kernel(
    const float* __restrict__ x, const float* __restrict__ w,
    const float* __restrict__ seqf, float* __restrict__ zq,
    double* __restrict__ loss_acc)
{
    const int t   = threadIdx.x;
    const int nb  = blockIdx.x;
    const int b   = nb >> 6;
    const int hw0 = (nb & 63) << 6;
    const int r   = t & 63;
    const int cg  = t >> 6;
    const float* xb = x  + (size_t)b * CHW_ + hw0;
    float*       zb = zq + (size_t)b * CHW_ + hw0;
    const int idx = (int)seqf[b * HW_ + hw0 + r];
    const float* wrow = w + (size_t)idx * C_;

    float lsum = 0.f;
#pragma unroll 4
    for (int cc = 0; cc < 64; ++cc) {
        const int c = cg * 64 + cc;
        const float xv = xb[(size_t)c * HW_ + r];
        const float d  = wrow[c] - xv;
        zb[(size_t)c * HW_ + r] = xv + d;
        lsum += d * d;
    }
#pragma unroll
    for (int off = 32; off >= 1; off >>= 1) lsum += __shfl_down(lsum, off, 64);
    __shared__ float wsum[4];
    if ((t & 63) == 0) wsum[t >> 6] = lsum;
    __syncthreads();
    if (t == 0)
        atomicAdd(loss_acc, (double)(wsum[0] + wsum[1] + wsum[2] + wsum[3]));
}

__global__ void finalize_kernel(const double* __restrict__ acc, float* __restrict__ loss_out)
{
    const double s = *acc;
    const float m = (float)(s / (double)((size_t)N_ * C_));
    loss_out[0] = m;
    loss_out[1] = m;
}

extern "C" void kernel_launch(void* const* d_in, const int* in_sizes, int n_in,
                              void* d_out, int out_size, void* d_ws, size_t ws_size,
                              hipStream_t stream)
{
    (void)in_sizes; (void)n_in; (void)out_size; (void)d_ws; (void)ws_size;
    const float* x = (const float*)d_in[0];
    const float* w = (const float*)d_in[1];
    float* out = (float*)d_out;

    float*          w_t    = out + WT_F;
    float*          wn     = out + WN_F;
    unsigned short* whb    = (unsigned short*)(out + WHB_F);
    unsigned short* wlb    = (unsigned short*)(out + WLB_F);
    int*            rlist  = (int*)(out + RLIST_F);
    int*            rcount = (int*)(out + RCNT_F);
    float*          seq    = out + SEQ_OFF;
    double*         loss_acc = (double*)(out + LOSS_OFF);

    transpose_w_kernel<<<256, 256, 0, stream>>>(w, w_t);
    wnorm_kernel<<<4, 256, 0, stream>>>(w, wn);
    wsplit_kernel<<<256, 256, 0, stream>>>(w, whb, wlb);
    hipMemsetAsync((void*)rcount, 0, 4, stream);
    argmin_mfma_kernel<<<256, 512, 0, stream>>>(x, whb, wlb, wn, seq, rlist, rcount);
    rescue_kernel<<<1024, 256, 0, stream>>>(x, w_t, wn, rlist, rcount, seq);
    hipMemsetAsync((char*)d_out + (size_t)LOSS_OFF * 4, 0, 8, stream);
    gather_kernel<<<1024, 256, 0, stream>>>(x, w, seq, out, loss_acc);
    finalize_kernel<<<1, 1, 0, stream>>>(loss_acc, out + LOSS_OFF);
}